// Round 3
// baseline (340.434 us; speedup 1.0000x reference)
//
#include <hip/hip_runtime.h>

#define NTOT 12288
#define DIM  256
#define KP   768            // packed K = 3 segments of 256 (hh + hl + lh)
#define NB   2
#define BM   256
#define BN   256
#define BK   32             // K elems per LDS tile
#define KT   (KP / BK)      // 24 K-tiles
#define TILEB 32768         // bytes per LDS buffer (A 16KB + B 16KB)

typedef __attribute__((ext_vector_type(8))) short bf16x8;
typedef __attribute__((ext_vector_type(16))) float f32x16;

// ---------- ordered-uint encoding for float atomicMax ----------
__device__ __forceinline__ unsigned toOrd(float f) {
    unsigned u = __float_as_uint(f);
    return (u & 0x80000000u) ? ~u : (u | 0x80000000u);
}
__device__ __forceinline__ float fromOrd(unsigned u) {
    unsigned b = (u & 0x80000000u) ? (u ^ 0x80000000u) : ~u;
    return __uint_as_float(b);
}
__device__ __forceinline__ ushort f2bf(float x) {          // RNE float->bf16
    unsigned u = __float_as_uint(x);
    unsigned r = (u + 0x7FFFu + ((u >> 16) & 1u)) >> 16;
    return (ushort)r;
}
__device__ __forceinline__ float bf2f(ushort h) { return __uint_as_float(((unsigned)h) << 16); }

__device__ __forceinline__ void load_lds16(const void* g, void* l) {
    __builtin_amdgcn_global_load_lds(
        (const __attribute__((address_space(1))) unsigned int*)g,
        (__attribute__((address_space(3))) unsigned int*)l, 16, 0, 0);
}

// ws layout:
//   [0,64)            int cnts[4]: [0..1]=nval[b], [2..3]=ninv[b]
//   [64, +96KB)       int dest[NB*NTOT]
//   [98368, +96KB)    unsigned maxsim[NB*NTOT]
//   [262144, +36MB)   ushort pk[NB][NTOT][KP]   (valid rows from front: [h|l|h],
//                                               invalid from back: [h|h|l])

// ---------------- kernel 1: per-batch scan -> destinations, init maxsim ----------------
__global__ __launch_bounds__(1024) void k_scan(
    const int* __restrict__ mask, int* __restrict__ dest,
    unsigned* __restrict__ maxsim, int* __restrict__ cnts)
{
    int b = blockIdx.x;
    int tid = threadIdx.x;
    int lane = tid & 63, w = tid >> 6;       // 16 waves
    __shared__ int wsum[16];
    int running = 0;
    for (int c0 = 0; c0 < NTOT; c0 += 1024) {
        int i = c0 + tid;
        int m = mask[b * NTOT + i] ? 1 : 0;
        int v = m;
        #pragma unroll
        for (int off = 1; off < 64; off <<= 1) {
            int t = __shfl_up(v, off);
            if (lane >= off) v += t;
        }
        if (lane == 63) wsum[w] = v;
        __syncthreads();
        int woff = 0, ctot = 0;
        #pragma unroll
        for (int k = 0; k < 16; k++) { int s = wsum[k]; ctot += s; if (k < w) woff += s; }
        int ex = running + woff + v - m;          // exclusive prefix of "valid"
        dest[b * NTOT + i] = m ? ex : (NTOT - 1 - (i - ex));
        maxsim[b * NTOT + i] = 0u;                // decodes to NaN -> never confident
        running += ctot;
        __syncthreads();
    }
    if (tid == 0) { cnts[b] = running; cnts[NB + b] = NTOT - running; }
}

// ---------------- kernel 2: normalize + compact into packed 768-wide bf16 rows ----------------
__global__ __launch_bounds__(256) void k_norm(
    const float* __restrict__ feat, const int* __restrict__ mask,
    const int* __restrict__ dest, ushort* __restrict__ pk)
{
    int tid = threadIdx.x;
    int w = tid >> 6, lane = tid & 63;
    int row = blockIdx.x * 4 + w;                 // [0, NB*NTOT)
    int b = row / NTOT;

    const float4 v = reinterpret_cast<const float4*>(feat + (size_t)row * DIM)[lane];
    float ss = v.x * v.x + v.y * v.y + v.z * v.z + v.w * v.w;
    #pragma unroll
    for (int off = 32; off; off >>= 1) ss += __shfl_xor(ss, off);
    float inv = 1.0f / fmaxf(sqrtf(ss), 1e-12f);

    int d = dest[row];
    int mv = mask[row];                           // wave-uniform
    float x[4] = {v.x * inv, v.y * inv, v.z * inv, v.w * inv};
    ushort4 h4, l4;
    ushort* hp = (ushort*)&h4; ushort* lp = (ushort*)&l4;
    #pragma unroll
    for (int j = 0; j < 4; j++) {
        ushort h = f2bf(x[j]);
        hp[j] = h;
        lp[j] = f2bf(x[j] - bf2f(h));
    }
    ushort* base = pk + (size_t)(b * NTOT + d) * KP;
    reinterpret_cast<ushort4*>(base)[lane] = h4;              // seg0 = h always
    if (mv) {   // valid: [h | l | h]
        reinterpret_cast<ushort4*>(base + 256)[lane] = l4;
        reinterpret_cast<ushort4*>(base + 512)[lane] = h4;
    } else {    // invalid: [h | h | l]
        reinterpret_cast<ushort4*>(base + 256)[lane] = h4;
        reinterpret_cast<ushort4*>(base + 512)[lane] = l4;
    }
}

// -------- kernel 3: pipelined bf16 GEMM (inv rows x val cols), row-max epilogue --------
__global__ __launch_bounds__(512, 2) void k_gemm(
    const ushort* __restrict__ pk, unsigned* __restrict__ maxsim, const int* __restrict__ cnts)
{
    int b = blockIdx.z;
    int nval = cnts[b];
    int ninv = cnts[NB + b];
    if ((int)blockIdx.x * BM >= ninv || (int)blockIdx.y * BN >= nval) return;
    int rowA0 = (NTOT - ninv) + blockIdx.x * BM;  // compacted invalid rows
    int colB0 = blockIdx.y * BN;                  // compacted valid rows

    __shared__ __align__(16) char smem[4 * TILEB];   // 128 KiB, 4-deep circular

    int tid = threadIdx.x, lane = tid & 63, w = tid >> 6;
    int wr = w >> 2, wc = w & 3;                  // 2M x 4N waves, each owns 128x64
    const ushort* pbase = pk + (size_t)b * NTOT * KP;

    // ---- staging setup: wave w loads A-chunks {w,w+8}, B-chunks {w,w+8} (1KB each) ----
    // chunk c covers tile rows [c*16, c*16+16); lane l -> dest byte c*1024 + l*16
    // dest (row r, colbyte cb) gets global colbyte cb ^ (((r>>1)&3)<<4)  (involution)
    const char* gsrc[4];
    int ldsoff[4];
    #pragma unroll
    for (int j = 0; j < 4; j++) {
        int isB = j & 1;
        int c = w + (j >> 1) * 8;
        int r = c * 16 + (lane >> 2);
        int rg = (isB ? colB0 : rowA0) + r;
        if (rg > NTOT - 1) rg = NTOT - 1;
        int cb = ((lane & 3) * 16) ^ (((r >> 1) & 3) << 4);
        gsrc[j]   = (const char*)(pbase + (size_t)rg * KP) + cb;
        ldsoff[j] = isB * 16384 + c * 1024;
    }

    // ---- fragment ds_read byte offsets (swizzled), fixed per lane ----
    int aoff[4][2], boff[2][2];
    #pragma unroll
    for (int mt = 0; mt < 4; mt++)
        #pragma unroll
        for (int ks = 0; ks < 2; ks++) {
            int row = wr * 128 + mt * 32 + (lane & 31);
            int cb  = (ks * 32 + ((lane >> 5) << 4)) ^ (((row >> 1) & 3) << 4);
            aoff[mt][ks] = row * 64 + cb;
        }
    #pragma unroll
    for (int nt = 0; nt < 2; nt++)
        #pragma unroll
        for (int ks = 0; ks < 2; ks++) {
            int row = wc * 64 + nt * 32 + (lane & 31);
            int cb  = (ks * 32 + ((lane >> 5) << 4)) ^ (((row >> 1) & 3) << 4);
            boff[nt][ks] = 16384 + row * 64 + cb;
        }

    f32x16 acc[4][2];
    #pragma unroll
    for (int mt = 0; mt < 4; mt++)
        #pragma unroll
        for (int nt = 0; nt < 2; nt++)
            #pragma unroll
            for (int e = 0; e < 16; e++) acc[mt][nt][e] = 0.0f;

    // ---- prologue: stage tiles 0,1,2; wait tile0 (<=8 outstanding) ----
    #pragma unroll
    for (int t = 0; t < 3; t++) {
        int bufo = (t & 3) * TILEB;
        #pragma unroll
        for (int j = 0; j < 4; j++)
            load_lds16(gsrc[j] + t * 64, smem + bufo + ldsoff[j]);
    }
    asm volatile("s_waitcnt vmcnt(8)" ::: "memory");
    __builtin_amdgcn_s_barrier();
    __builtin_amdgcn_sched_barrier(0);

    // ---- main loop: 24 K-tiles; stage t+3; counted vmcnt; setprio around MFMA ----
    for (int t = 0; t < KT; ++t) {
        const char* sb = smem + (t & 3) * TILEB;

        bf16x8 af[4][2], bg[2][2];
        #pragma unroll
        for (int mt = 0; mt < 4; mt++)
            #pragma unroll
            for (int ks = 0; ks < 2; ks++)
                af[mt][ks] = *(const bf16x8*)(sb + aoff[mt][ks]);
        #pragma unroll
        for (int nt = 0; nt < 2; nt++)
            #pragma unroll
            for (int ks = 0; ks < 2; ks++)
                bg[nt][ks] = *(const bf16x8*)(sb + boff[nt][ks]);

        if (t + 3 < KT) {
            int bufo = ((t + 3) & 3) * TILEB;
            #pragma unroll
            for (int j = 0; j < 4; j++)
                load_lds16(gsrc[j] + (t + 3) * 64, smem + bufo + ldsoff[j]);
        }

        __builtin_amdgcn_s_setprio(1);
        #pragma unroll
        for (int ks = 0; ks < 2; ks++)
            #pragma unroll
            for (int mt = 0; mt < 4; mt++)
                #pragma unroll
                for (int nt = 0; nt < 2; nt++)
                    acc[mt][nt] = __builtin_amdgcn_mfma_f32_32x32x16_bf16(
                        af[mt][ks], bg[nt][ks], acc[mt][nt], 0, 0, 0);
        __builtin_amdgcn_s_setprio(0);
        __builtin_amdgcn_sched_barrier(0);

        if (t < KT - 3)       asm volatile("s_waitcnt vmcnt(8)" ::: "memory");
        else if (t == KT - 3) asm volatile("s_waitcnt vmcnt(4)" ::: "memory");
        else                  asm volatile("s_waitcnt vmcnt(0)" ::: "memory");
        __builtin_amdgcn_s_barrier();
        __builtin_amdgcn_sched_barrier(0);
    }

    // ---- epilogue: per-row max over this block's cols, butterfly over 32-lane groups ----
    int cl = lane & 31, hh = lane >> 5;
    int cg0 = colB0 + wc * 64 + cl;
    int cg1 = cg0 + 32;
    bool v0 = cg0 < nval, v1 = cg1 < nval;
    #pragma unroll
    for (int mt = 0; mt < 4; mt++) {
        float mrow[16];
        #pragma unroll
        for (int rr = 0; rr < 16; rr++) {
            float a0 = v0 ? acc[mt][0][rr] : -INFINITY;
            float a1 = v1 ? acc[mt][1][rr] : -INFINITY;
            mrow[rr] = fmaxf(a0, a1);
        }
        #pragma unroll
        for (int off = 1; off <= 16; off <<= 1)
            #pragma unroll
            for (int rr = 0; rr < 16; rr++)
                mrow[rr] = fmaxf(mrow[rr], __shfl_xor(mrow[rr], off));
        if (cl == 0) {
            #pragma unroll
            for (int rr = 0; rr < 16; rr++) {
                int rowg = rowA0 + wr * 128 + mt * 32 + (rr & 3) + 8 * (rr >> 2) + 4 * hh;
                if (rowg < NTOT)
                    atomicMax(maxsim + (size_t)b * NTOT + rowg, toOrd(mrow[rr]));
            }
        }
    }
}

// ---------------- kernel 4: finalize scalar ----------------
__global__ __launch_bounds__(256) void k_final(
    const unsigned* __restrict__ maxsim, const int* __restrict__ cnts, float* __restrict__ out)
{
    __shared__ float ssum[NB];
    __shared__ int   scnt[NB];
    int tid = threadIdx.x;
    if (tid < NB) { ssum[tid] = 0.0f; scnt[tid] = 0; }
    __syncthreads();

    for (int b = 0; b < NB; b++) {
        int ninv = cnts[NB + b];
        float ls = 0.0f; int lc = 0;
        for (int i = tid; i < ninv; i += 256) {
            int r = NTOT - ninv + i;
            float ms = fromOrd(maxsim[(size_t)b * NTOT + r]);
            if (ms > 0.8f) { ls += 1.0f - ms; lc++; }   // NaN-safe
        }
        #pragma unroll
        for (int off = 32; off; off >>= 1) {
            ls += __shfl_xor(ls, off);
            lc += __shfl_xor(lc, off);
        }
        if ((tid & 63) == 0) { atomicAdd(&ssum[b], ls); atomicAdd(&scnt[b], lc); }
    }
    __syncthreads();

    if (tid == 0) {
        float tl = 0.0f, tp = 0.0f;
        for (int b = 0; b < NB; b++) {
            int nval = cnts[b], ninv = cnts[NB + b], nc = scnt[b];
            bool active = (nc > 0) && (nval > 0) && (ninv > 0);
            if (active) {
                float pseudo = ssum[b] / (float)(nc > 0 ? nc : 1);
                tl += pseudo * (float)ninv;
                tp += (float)ninv;
            }
        }
        out[0] = (tp > 0.0f) ? (0.01f * tl / tp) : 0.0f;
    }
}

extern "C" void kernel_launch(void* const* d_in, const int* in_sizes, int n_in,
                              void* d_out, int out_size, void* d_ws, size_t ws_size,
                              hipStream_t stream)
{
    const float* feat = (const float*)d_in[0];
    const int*   mask = (const int*)d_in[1];

    char* ws = (char*)d_ws;
    int*      cnts   = (int*)ws;
    int*      dest   = (int*)(ws + 64);
    unsigned* maxsim = (unsigned*)(ws + 98368);
    ushort*   pk     = (ushort*)(ws + 262144);

    hipLaunchKernelGGL(k_scan, dim3(NB), dim3(1024), 0, stream, mask, dest, maxsim, cnts);
    hipLaunchKernelGGL(k_norm, dim3(NB * NTOT / 4), dim3(256), 0, stream, feat, mask, dest, pk);
    hipLaunchKernelGGL(k_gemm, dim3(NTOT / BM, NTOT / BN, NB), dim3(512), 0, stream,
                       pk, maxsim, cnts);
    hipLaunchKernelGGL(k_final, dim3(1), dim3(256), 0, stream, maxsim, cnts, (float*)d_out);
}

// Round 4
// 238.705 us; speedup vs baseline: 1.4262x; 1.4262x over previous
//
#include <hip/hip_runtime.h>

#define NTOT 12288
#define DIM  256
#define NB   2
#define BM   128
#define BN   128
#define NKT  8            // K-steps: 256 / 32
#define ABUF 16384        // bytes per K-step buffer (A 8KB + B 8KB)
#define GP   64           // 64x64 tile grid covers ninv/nval up to 8192 (>> 6144+18sigma)

typedef __attribute__((ext_vector_type(8))) _Float16 f16x8;
typedef __attribute__((ext_vector_type(16))) float f32x16;

// ---------- ordered-uint encoding for float atomicMax ----------
__device__ __forceinline__ unsigned toOrd(float f) {
    unsigned u = __float_as_uint(f);
    return (u & 0x80000000u) ? ~u : (u | 0x80000000u);
}
__device__ __forceinline__ float fromOrd(unsigned u) {
    unsigned b = (u & 0x80000000u) ? (u ^ 0x80000000u) : ~u;
    return __uint_as_float(b);
}
__device__ __forceinline__ void load_lds16(const void* g, void* l) {
    __builtin_amdgcn_global_load_lds(
        (const __attribute__((address_space(1))) unsigned int*)g,
        (__attribute__((address_space(3))) unsigned int*)l, 16, 0, 0);
}

// ws layout:
//   [0,64)           int cnts[4]: [0..1]=nval[b], [2..3]=ninv[b]
//   [64, +96KB)      int inv[NB*NTOT]      (dest -> source index)
//   [98368, +96KB)   unsigned maxsim[NB*NTOT]
//   [262144, +12.6MB) ushort pk[NB][384 panels][16 chunks][512]  fragment-linear fp16:
//        element (point d, k) at tile t=(d>>5)*16+(k>>4), half-offset ((k>>3&1)*32+(d&31))*8+(k&7)

// ---------------- kernel 1: per-batch scan -> inverse permutation, init maxsim ----------------
__global__ __launch_bounds__(1024) void k_scan(
    const int* __restrict__ mask, int* __restrict__ inv,
    unsigned* __restrict__ maxsim, int* __restrict__ cnts)
{
    int b = blockIdx.x;
    int tid = threadIdx.x;
    int lane = tid & 63, w = tid >> 6;        // 16 waves
    __shared__ int wsum[16];
    int running = 0;
    for (int c0 = 0; c0 < NTOT; c0 += 1024) {
        int i = c0 + tid;
        int m = mask[b * NTOT + i] ? 1 : 0;
        int v = m;
        #pragma unroll
        for (int off = 1; off < 64; off <<= 1) {
            int t = __shfl_up(v, off);
            if (lane >= off) v += t;
        }
        if (lane == 63) wsum[w] = v;
        __syncthreads();
        int woff = 0, ctot = 0;
        #pragma unroll
        for (int k = 0; k < 16; k++) { int s = wsum[k]; ctot += s; if (k < w) woff += s; }
        int ex = running + woff + v - m;           // exclusive prefix of "valid"
        int d = m ? ex : (NTOT - 1 - (i - ex));    // invalid packed from the back
        inv[b * NTOT + d] = i;
        maxsim[b * NTOT + i] = 0u;                 // decodes to NaN -> never confident
        running += ctot;
        __syncthreads();
    }
    if (tid == 0) { cnts[b] = running; cnts[NB + b] = NTOT - running; }
}

// ------- kernel 2: gather + normalize + write fp16 in MFMA-fragment-linear layout -------
__global__ __launch_bounds__(256) void k_norm(
    const float* __restrict__ feat, const int* __restrict__ inv, ushort* __restrict__ pk)
{
    int blk = blockIdx.x;
    int b = blk / (NTOT / 32);
    int panel = blk % (NTOT / 32);
    int tid = threadIdx.x;
    int r = tid >> 3, c = tid & 7;           // 32 rows x 8 k-slices
    int d = panel * 32 + r;
    int i = inv[b * NTOT + d];
    const float* src = feat + ((size_t)b * NTOT + i) * DIM + c * 32;

    float x[32]; float ss = 0.f;
    #pragma unroll
    for (int j = 0; j < 8; j++) {
        float4 v = *(const float4*)(src + j * 4);
        x[j*4+0] = v.x; x[j*4+1] = v.y; x[j*4+2] = v.z; x[j*4+3] = v.w;
        ss += v.x*v.x + v.y*v.y + v.z*v.z + v.w*v.w;
    }
    ss += __shfl_xor(ss, 1); ss += __shfl_xor(ss, 2); ss += __shfl_xor(ss, 4);
    float invn = 1.0f / fmaxf(sqrtf(ss), 1e-12f);

    ushort* pbout = pk + (size_t)b * NTOT * DIM;
    #pragma unroll
    for (int g = 0; g < 4; g++) {            // 4 groups of 8 halfs -> 16B stores
        f16x8 hv;
        #pragma unroll
        for (int e = 0; e < 8; e++) hv[e] = (_Float16)(x[g*8+e] * invn);
        int kc = c * 2 + (g >> 1), kh = g & 1;
        *(f16x8*)(pbout + (size_t)(panel * 16 + kc) * 512 + (kh * 32 + r) * 8) = hv;
    }
}

// -------- kernel 3: m97-style fp16 MFMA GEMM (inv rows x val cols), row-max epilogue --------
__global__ __launch_bounds__(256, 3) void k_gemm(
    const ushort* __restrict__ pk, unsigned* __restrict__ maxsim, const int* __restrict__ cnts)
{
    int b = blockIdx.z;
    int nval = cnts[b];
    int ninv = cnts[NB + b];
    int bx = blockIdx.x;     // col tile
    int by = blockIdx.y;     // row tile (from back, keeps panels 32-aligned)
    if (by * BM >= ninv || bx * BN >= nval) return;
    int rowA0 = NTOT - (by + 1) * BM;
    int colB0 = bx * BN;
    int pA0 = rowA0 >> 5, pB0 = colB0 >> 5;

    __shared__ __align__(16) char smem[3 * ABUF];   // 48 KiB, 3-deep circular

    int tid = threadIdx.x, lane = tid & 63, w = tid >> 6;
    int wr = w >> 1, wc = w & 1;                    // 2x2 waves, each 64x64 out
    const ushort* pb = pk + (size_t)b * NTOT * DIM;

    // stage assignment: wave w loads A panel pA0+w (2 chunks) + B panel pB0+w (2 chunks)
    const ushort* gsrc[4];
    int ldso[4];
    gsrc[0] = pb + ((size_t)(pA0 + w) * 16 + 0) * 512 + lane * 8;
    gsrc[1] = pb + ((size_t)(pA0 + w) * 16 + 1) * 512 + lane * 8;
    gsrc[2] = pb + ((size_t)(pB0 + w) * 16 + 0) * 512 + lane * 8;
    gsrc[3] = pb + ((size_t)(pB0 + w) * 16 + 1) * 512 + lane * 8;
    ldso[0] = (w * 2 + 0) * 1024;
    ldso[1] = (w * 2 + 1) * 1024;
    ldso[2] = 8192 + (w * 2 + 0) * 1024;
    ldso[3] = 8192 + (w * 2 + 1) * 1024;

    // fragment read offsets: wave-uniform tile base + lane*16 (contiguous, conflict-free)
    int aoff[2][2], boff[2][2];
    #pragma unroll
    for (int mt = 0; mt < 2; mt++)
        #pragma unroll
        for (int ks = 0; ks < 2; ks++)
            aoff[mt][ks] = ((wr * 2 + mt) * 2 + ks) * 1024 + lane * 16;
    #pragma unroll
    for (int nt = 0; nt < 2; nt++)
        #pragma unroll
        for (int ks = 0; ks < 2; ks++)
            boff[nt][ks] = 8192 + ((wc * 2 + nt) * 2 + ks) * 1024 + lane * 16;

    f32x16 acc[2][2];
    #pragma unroll
    for (int mt = 0; mt < 2; mt++)
        #pragma unroll
        for (int nt = 0; nt < 2; nt++)
            #pragma unroll
            for (int e = 0; e < 16; e++) acc[mt][nt][e] = 0.0f;

#define STAGE(t) { const int bo_ = ((t) % 3) * ABUF;                          \
    _Pragma("unroll")                                                         \
    for (int j_ = 0; j_ < 4; j_++)                                            \
        load_lds16(gsrc[j_] + (t) * 1024, smem + bo_ + ldso[j_]); }

    STAGE(0); STAGE(1);
    asm volatile("s_waitcnt vmcnt(4)" ::: "memory");
    __builtin_amdgcn_s_barrier();
    __builtin_amdgcn_sched_barrier(0);

    #pragma unroll
    for (int kt = 0; kt < NKT; ++kt) {
        const char* sb = smem + (kt % 3) * ABUF;
        f16x8 af[2][2], bg[2][2];
        #pragma unroll
        for (int mt = 0; mt < 2; mt++)
            #pragma unroll
            for (int ks = 0; ks < 2; ks++)
                af[mt][ks] = *(const f16x8*)(sb + aoff[mt][ks]);
        #pragma unroll
        for (int nt = 0; nt < 2; nt++)
            #pragma unroll
            for (int ks = 0; ks < 2; ks++)
                bg[nt][ks] = *(const f16x8*)(sb + boff[nt][ks]);

        if (kt + 2 < NKT) STAGE(kt + 2);

        #pragma unroll
        for (int ks = 0; ks < 2; ks++)
            #pragma unroll
            for (int mt = 0; mt < 2; mt++)
                #pragma unroll
                for (int nt = 0; nt < 2; nt++)
                    acc[mt][nt] = __builtin_amdgcn_mfma_f32_32x32x16_f16(
                        af[mt][ks], bg[nt][ks], acc[mt][nt], 0, 0, 0);
        __builtin_amdgcn_sched_barrier(0);

        if (kt < NKT - 2)       asm volatile("s_waitcnt vmcnt(4)" ::: "memory");
        else if (kt == NKT - 2) asm volatile("s_waitcnt vmcnt(0)" ::: "memory");
        if (kt < NKT - 1) {
            __builtin_amdgcn_s_barrier();
            __builtin_amdgcn_sched_barrier(0);
        }
    }
#undef STAGE

    // ---- epilogue: per-row max over block cols, butterfly over 32-lane col groups ----
    int cl = lane & 31, hh = lane >> 5;
    int cg0 = colB0 + wc * 64 + cl;
    int cg1 = cg0 + 32;
    bool v0 = cg0 < nval, v1 = cg1 < nval;
    #pragma unroll
    for (int mt = 0; mt < 2; mt++) {
        float mrow[16];
        #pragma unroll
        for (int rr = 0; rr < 16; rr++) {
            float a0 = v0 ? acc[mt][0][rr] : -INFINITY;
            float a1 = v1 ? acc[mt][1][rr] : -INFINITY;
            mrow[rr] = fmaxf(a0, a1);
        }
        #pragma unroll
        for (int off = 1; off <= 16; off <<= 1)
            #pragma unroll
            for (int rr = 0; rr < 16; rr++)
                mrow[rr] = fmaxf(mrow[rr], __shfl_xor(mrow[rr], off));
        if (cl == 0) {
            #pragma unroll
            for (int rr = 0; rr < 16; rr++) {
                int rowg = rowA0 + wr * 64 + mt * 32 + (rr & 3) + 8 * (rr >> 2) + 4 * hh;
                atomicMax(maxsim + (size_t)b * NTOT + rowg, toOrd(mrow[rr]));
            }
        }
    }
}

// ---------------- kernel 4: finalize scalar ----------------
__global__ __launch_bounds__(256) void k_final(
    const unsigned* __restrict__ maxsim, const int* __restrict__ cnts, float* __restrict__ out)
{
    __shared__ float ssum[NB];
    __shared__ int   scnt[NB];
    int tid = threadIdx.x;
    if (tid < NB) { ssum[tid] = 0.0f; scnt[tid] = 0; }
    __syncthreads();

    for (int b = 0; b < NB; b++) {
        int ninv = cnts[NB + b];
        float ls = 0.0f; int lc = 0;
        for (int i = tid; i < ninv; i += 256) {
            int r = NTOT - ninv + i;
            float ms = fromOrd(maxsim[(size_t)b * NTOT + r]);
            if (ms > 0.8f) { ls += 1.0f - ms; lc++; }   // NaN-safe
        }
        #pragma unroll
        for (int off = 32; off; off >>= 1) {
            ls += __shfl_xor(ls, off);
            lc += __shfl_xor(lc, off);
        }
        if ((tid & 63) == 0) { atomicAdd(&ssum[b], ls); atomicAdd(&scnt[b], lc); }
    }
    __syncthreads();

    if (tid == 0) {
        float tl = 0.0f, tp = 0.0f;
        for (int b = 0; b < NB; b++) {
            int nval = cnts[b], ninv = cnts[NB + b], nc = scnt[b];
            bool active = (nc > 0) && (nval > 0) && (ninv > 0);
            if (active) {
                float pseudo = ssum[b] / (float)(nc > 0 ? nc : 1);
                tl += pseudo * (float)ninv;
                tp += (float)ninv;
            }
        }
        out[0] = (tp > 0.0f) ? (0.01f * tl / tp) : 0.0f;
    }
}

extern "C" void kernel_launch(void* const* d_in, const int* in_sizes, int n_in,
                              void* d_out, int out_size, void* d_ws, size_t ws_size,
                              hipStream_t stream)
{
    const float* feat = (const float*)d_in[0];
    const int*   mask = (const int*)d_in[1];

    char* ws = (char*)d_ws;
    int*      cnts   = (int*)ws;
    int*      inv    = (int*)(ws + 64);
    unsigned* maxsim = (unsigned*)(ws + 98368);
    ushort*   pk     = (ushort*)(ws + 262144);

    hipLaunchKernelGGL(k_scan, dim3(NB), dim3(1024), 0, stream, mask, inv, maxsim, cnts);
    hipLaunchKernelGGL(k_norm, dim3(NB * (NTOT / 32)), dim3(256), 0, stream, feat, inv, pk);
    hipLaunchKernelGGL(k_gemm, dim3(GP, GP, NB), dim3(256), 0, stream, pk, maxsim, cnts);
    hipLaunchKernelGGL(k_final, dim3(1), dim3(256), 0, stream, maxsim, cnts, (float*)d_out);
}

// Round 5
// 159.289 us; speedup vs baseline: 2.1372x; 1.4986x over previous
//
#include <hip/hip_runtime.h>

#define NTOT 12288
#define DIM  256
#define NB   2
#define BROWS 512         // rows per block (8 waves x 64)
#define CGRP  256         // cols per block group (4 B-tiles of 64)
#define NT    4           // B-tiles per block
#define TILEB 32768       // bytes per B-tile in LDS (64 cols x 256 k fp16)
#define NGC   32          // col-group grid (covers nval <= 8192)
#define NRB   16          // row-block grid (covers ninv <= 8192)

typedef __attribute__((ext_vector_type(8))) _Float16 f16x8;
typedef __attribute__((ext_vector_type(16))) float f32x16;

// ---------- ordered-uint encoding for float atomicMax ----------
__device__ __forceinline__ unsigned toOrd(float f) {
    unsigned u = __float_as_uint(f);
    return (u & 0x80000000u) ? ~u : (u | 0x80000000u);
}
__device__ __forceinline__ float fromOrd(unsigned u) {
    unsigned b = (u & 0x80000000u) ? (u ^ 0x80000000u) : ~u;
    return __uint_as_float(b);
}
__device__ __forceinline__ void load_lds16(const void* g, void* l) {
    __builtin_amdgcn_global_load_lds(
        (const __attribute__((address_space(1))) unsigned int*)g,
        (__attribute__((address_space(3))) unsigned int*)l, 16, 0, 0);
}

// ws layout:
//   [0,64)            int cnts[4]: [0..1]=nval[b], [2..3]=ninv[b]
//   [64, +96KB)       int inv[NB*NTOT]   (dest -> source index)
//   [98368, +96KB)    unsigned maxsim[NB*NTOT]
//   [262144, +12.6MB) ushort pk[NB][384 panels][16 chunks][512] fragment-linear fp16

// ---------------- kernel 1: per-batch scan (prefetched) -> inverse perm, init maxsim ----------------
__global__ __launch_bounds__(1024) void k_scan(
    const int* __restrict__ mask, int* __restrict__ inv,
    unsigned* __restrict__ maxsim, int* __restrict__ cnts)
{
    int b = blockIdx.x;
    int tid = threadIdx.x;
    int lane = tid & 63, w = tid >> 6;        // 16 waves
    __shared__ int wsum[16];

    int mv[12];
    #pragma unroll
    for (int j = 0; j < 12; j++) mv[j] = mask[b * NTOT + j * 1024 + tid] ? 1 : 0;

    int running = 0;
    #pragma unroll
    for (int j = 0; j < 12; j++) {
        int i = j * 1024 + tid;
        int m = mv[j];
        int v = m;
        #pragma unroll
        for (int off = 1; off < 64; off <<= 1) {
            int t = __shfl_up(v, off);
            if (lane >= off) v += t;
        }
        if (lane == 63) wsum[w] = v;
        __syncthreads();
        int woff = 0, ctot = 0;
        #pragma unroll
        for (int k = 0; k < 16; k++) { int s = wsum[k]; ctot += s; if (k < w) woff += s; }
        int ex = running + woff + v - m;           // exclusive prefix of "valid"
        int d = m ? ex : (NTOT - 1 - (i - ex));    // invalid packed from the back
        inv[b * NTOT + d] = i;
        maxsim[b * NTOT + i] = 0u;                 // decodes to NaN -> never confident
        running += ctot;
        __syncthreads();
    }
    if (tid == 0) { cnts[b] = running; cnts[NB + b] = NTOT - running; }
}

// ------- kernel 2: gather + normalize + write fp16 in MFMA-fragment-linear layout -------
__global__ __launch_bounds__(256) void k_norm(
    const float* __restrict__ feat, const int* __restrict__ inv, ushort* __restrict__ pk)
{
    int blk = blockIdx.x;
    int b = blk / (NTOT / 32);
    int panel = blk % (NTOT / 32);
    int tid = threadIdx.x;
    int r = tid >> 3, c = tid & 7;           // 32 rows x 8 k-slices
    int d = panel * 32 + r;
    int i = inv[b * NTOT + d];
    const float* src = feat + ((size_t)b * NTOT + i) * DIM + c * 32;

    float x[32]; float ss = 0.f;
    #pragma unroll
    for (int j = 0; j < 8; j++) {
        float4 v = *(const float4*)(src + j * 4);
        x[j*4+0] = v.x; x[j*4+1] = v.y; x[j*4+2] = v.z; x[j*4+3] = v.w;
        ss += v.x*v.x + v.y*v.y + v.z*v.z + v.w*v.w;
    }
    ss += __shfl_xor(ss, 1); ss += __shfl_xor(ss, 2); ss += __shfl_xor(ss, 4);
    float invn = 1.0f / fmaxf(sqrtf(ss), 1e-12f);

    ushort* pbout = pk + (size_t)b * NTOT * DIM;
    #pragma unroll
    for (int g = 0; g < 4; g++) {            // 4 groups of 8 halfs -> 16B stores
        f16x8 hv;
        #pragma unroll
        for (int e = 0; e < 8; e++) hv[e] = (_Float16)(x[g*8+e] * invn);
        int kc = c * 2 + (g >> 1), kh = g & 1;
        *(f16x8*)(pbout + (size_t)(panel * 16 + kc) * 512 + (kh * 32 + r) * 8) = hv;
    }
}

// -------- kernel 3: A-in-register, B-streaming fp16 MFMA GEMM with running row-max --------
__global__ __launch_bounds__(512, 2) void k_gemm(
    const ushort* __restrict__ pk, unsigned* __restrict__ maxsim, const int* __restrict__ cnts)
{
    int b = blockIdx.z;
    int nval = cnts[b];
    int ninv = cnts[NB + b];
    int bx = blockIdx.x;     // col group
    int by = blockIdx.y;     // row block (from back)
    if (bx * CGRP >= nval || by * BROWS >= ninv) return;
    int rowA0 = NTOT - (by + 1) * BROWS;
    int colG0 = bx * CGRP;
    int pA0 = rowA0 >> 5, pBg = colG0 >> 5;

    __shared__ __align__(16) char smem[4 * TILEB];   // 128 KiB B-tile ring

    int tid = threadIdx.x, lane = tid & 63, w = tid >> 6;   // 8 waves, wave w: rows rowA0+w*64
    const ushort* pb = pk + (size_t)b * NTOT * DIM;

    // ---- A fragments resident in registers: 2 m-tiles x 16 k-slices = 128 VGPR ----
    f16x8 a[2][16];
    {
        const ushort* abase = pb + (size_t)(pA0 + w * 2) * 16 * 512 + lane * 8;
        #pragma unroll
        for (int mt = 0; mt < 2; mt++)
            #pragma unroll
            for (int ks = 0; ks < 16; ks++)
                a[mt][ks] = *(const f16x8*)(abase + (size_t)(mt * 16 + ks) * 512);
    }
    __builtin_amdgcn_sched_barrier(0);

    // stage B-tile t: 32 chunks of 1KB; wave w stages chunks w*4..w*4+3 (vmcnt 4/tile/wave)
#define STAGE(t) { const int bo_ = ((t) & 3) * TILEB; const int p0_ = pBg + (t) * 2;     \
    _Pragma("unroll")                                                                    \
    for (int c_ = 0; c_ < 4; c_++) {                                                     \
        int c__ = w * 4 + c_;                                                            \
        const ushort* g__ = pb + ((size_t)(p0_ + (c__ >> 4)) * 16 + (c__ & 15)) * 512 + lane * 8; \
        load_lds16(g__, smem + bo_ + c__ * 1024);                                        \
    }                                                                                    \
    __builtin_amdgcn_sched_barrier(0); }

    STAGE(0); STAGE(1); STAGE(2);

    float mrow[2][16];
    #pragma unroll
    for (int mt = 0; mt < 2; mt++)
        #pragma unroll
        for (int rr = 0; rr < 16; rr++) mrow[mt][rr] = -INFINITY;

    const f32x16 zacc = {};

    #pragma unroll
    for (int t = 0; t < NT; t++) {
        // wait own tile-t stage loads (keep up to 2 younger tiles in flight), then sync
        if (t <= 1)      asm volatile("s_waitcnt vmcnt(8)" ::: "memory");
        else if (t == 2) asm volatile("s_waitcnt vmcnt(4)" ::: "memory");
        else             asm volatile("s_waitcnt vmcnt(0)" ::: "memory");
        __builtin_amdgcn_s_barrier();
        __builtin_amdgcn_sched_barrier(0);
        if (t + 3 < NT) STAGE(t + 3);

        const char* sb = smem + (t & 3) * TILEB;
        #pragma unroll
        for (int nt = 0; nt < 2; nt++) {
            f32x16 acc[2] = {zacc, zacc};
            #pragma unroll
            for (int kq = 0; kq < 4; kq++) {
                f16x8 bg[4];
                #pragma unroll
                for (int k4 = 0; k4 < 4; k4++)
                    bg[k4] = *(const f16x8*)(sb + (nt * 16 + kq * 4 + k4) * 1024 + lane * 16);
                #pragma unroll
                for (int k4 = 0; k4 < 4; k4++)
                    #pragma unroll
                    for (int mt = 0; mt < 2; mt++)
                        acc[mt] = __builtin_amdgcn_mfma_f32_32x32x16_f16(
                            a[mt][kq * 4 + k4], bg[k4], acc[mt], 0, 0, 0);
            }
            // fold into running row-max (mask invalid cols)
            int cg = colG0 + t * 64 + nt * 32 + (lane & 31);
            bool cv = cg < nval;
            #pragma unroll
            for (int mt = 0; mt < 2; mt++)
                #pragma unroll
                for (int rr = 0; rr < 16; rr++) {
                    float vv = cv ? acc[mt][rr] : -INFINITY;
                    mrow[mt][rr] = fmaxf(mrow[mt][rr], vv);
                }
        }
    }
#undef STAGE

    // ---- epilogue: butterfly over 32-lane col groups, one atomic per row ----
    #pragma unroll
    for (int off = 1; off <= 16; off <<= 1)
        #pragma unroll
        for (int mt = 0; mt < 2; mt++)
            #pragma unroll
            for (int rr = 0; rr < 16; rr++)
                mrow[mt][rr] = fmaxf(mrow[mt][rr], __shfl_xor(mrow[mt][rr], off));

    int cl = lane & 31, hh = lane >> 5;
    if (cl == 0) {
        #pragma unroll
        for (int mt = 0; mt < 2; mt++)
            #pragma unroll
            for (int rr = 0; rr < 16; rr++) {
                int rowg = rowA0 + w * 64 + mt * 32 + (rr & 3) + 8 * (rr >> 2) + 4 * hh;
                atomicMax(maxsim + (size_t)b * NTOT + rowg, toOrd(mrow[mt][rr]));
            }
    }
}

// ---------------- kernel 4: finalize scalar ----------------
__global__ __launch_bounds__(256) void k_final(
    const unsigned* __restrict__ maxsim, const int* __restrict__ cnts, float* __restrict__ out)
{
    __shared__ float ssum[NB];
    __shared__ int   scnt[NB];
    int tid = threadIdx.x;
    if (tid < NB) { ssum[tid] = 0.0f; scnt[tid] = 0; }
    __syncthreads();

    for (int b = 0; b < NB; b++) {
        int ninv = cnts[NB + b];
        float ls = 0.0f; int lc = 0;
        for (int i = tid; i < ninv; i += 256) {
            int r = NTOT - ninv + i;
            float ms = fromOrd(maxsim[(size_t)b * NTOT + r]);
            if (ms > 0.8f) { ls += 1.0f - ms; lc++; }   // NaN-safe
        }
        #pragma unroll
        for (int off = 32; off; off >>= 1) {
            ls += __shfl_xor(ls, off);
            lc += __shfl_xor(lc, off);
        }
        if ((tid & 63) == 0) { atomicAdd(&ssum[b], ls); atomicAdd(&scnt[b], lc); }
    }
    __syncthreads();

    if (tid == 0) {
        float tl = 0.0f, tp = 0.0f;
        for (int b = 0; b < NB; b++) {
            int nval = cnts[b], ninv = cnts[NB + b], nc = scnt[b];
            bool active = (nc > 0) && (nval > 0) && (ninv > 0);
            if (active) {
                float pseudo = ssum[b] / (float)(nc > 0 ? nc : 1);
                tl += pseudo * (float)ninv;
                tp += (float)ninv;
            }
        }
        out[0] = (tp > 0.0f) ? (0.01f * tl / tp) : 0.0f;
    }
}

extern "C" void kernel_launch(void* const* d_in, const int* in_sizes, int n_in,
                              void* d_out, int out_size, void* d_ws, size_t ws_size,
                              hipStream_t stream)
{
    const float* feat = (const float*)d_in[0];
    const int*   mask = (const int*)d_in[1];

    char* ws = (char*)d_ws;
    int*      cnts   = (int*)ws;
    int*      inv    = (int*)(ws + 64);
    unsigned* maxsim = (unsigned*)(ws + 98368);
    ushort*   pk     = (ushort*)(ws + 262144);

    hipLaunchKernelGGL(k_scan, dim3(NB), dim3(1024), 0, stream, mask, inv, maxsim, cnts);
    hipLaunchKernelGGL(k_norm, dim3(NB * (NTOT / 32)), dim3(256), 0, stream, feat, inv, pk);
    hipLaunchKernelGGL(k_gemm, dim3(NGC, NRB, NB), dim3(512), 0, stream, pk, maxsim, cnts);
    hipLaunchKernelGGL(k_final, dim3(1), dim3(256), 0, stream, maxsim, cnts, (float*)d_out);
}

// Round 6
// 158.261 us; speedup vs baseline: 2.1511x; 1.0065x over previous
//
#include <hip/hip_runtime.h>

#define NTOT 12288
#define DIM  256
#define NB   2
#define BROWS 512         // rows per block (16 waves x 32)
#define CGRP  256         // cols per block group (4 B-tiles of 64)
#define NT    4           // B-tiles per block
#define TILEB 32768       // bytes per B-tile in LDS (64 cols x 256 k fp16)
#define NGC   32          // col-group grid (covers nval <= 8192)
#define NRB   16          // row-block grid (covers ninv <= 8192)

typedef __attribute__((ext_vector_type(8))) _Float16 f16x8;
typedef __attribute__((ext_vector_type(16))) float f32x16;

// ---------- ordered-uint encoding for float atomicMax ----------
__device__ __forceinline__ unsigned toOrd(float f) {
    unsigned u = __float_as_uint(f);
    return (u & 0x80000000u) ? ~u : (u | 0x80000000u);
}
__device__ __forceinline__ float fromOrd(unsigned u) {
    unsigned b = (u & 0x80000000u) ? (u ^ 0x80000000u) : ~u;
    return __uint_as_float(b);
}
__device__ __forceinline__ void load_lds16(const void* g, void* l) {
    __builtin_amdgcn_global_load_lds(
        (const __attribute__((address_space(1))) unsigned int*)g,
        (__attribute__((address_space(3))) unsigned int*)l, 16, 0, 0);
}

// ws layout:
//   [0,64)            int cnts[4]: [0..1]=nval[b], [2..3]=ninv[b]
//   [64, +96KB)       int inv[NB*NTOT]   (dest -> source index)
//   [98368, +96KB)    unsigned maxsim[NB*NTOT]
//   [262144, +12.6MB) ushort pk[NB][384 panels][16 chunks][512] fragment-linear fp16

// ---------------- kernel 1: per-batch scan (prefetched) -> inverse perm, init maxsim ----------------
__global__ __launch_bounds__(1024) void k_scan(
    const int* __restrict__ mask, int* __restrict__ inv,
    unsigned* __restrict__ maxsim, int* __restrict__ cnts)
{
    int b = blockIdx.x;
    int tid = threadIdx.x;
    int lane = tid & 63, w = tid >> 6;        // 16 waves
    __shared__ int wsum[16];

    int mv[12];
    #pragma unroll
    for (int j = 0; j < 12; j++) mv[j] = mask[b * NTOT + j * 1024 + tid] ? 1 : 0;

    int running = 0;
    #pragma unroll
    for (int j = 0; j < 12; j++) {
        int i = j * 1024 + tid;
        int m = mv[j];
        int v = m;
        #pragma unroll
        for (int off = 1; off < 64; off <<= 1) {
            int t = __shfl_up(v, off);
            if (lane >= off) v += t;
        }
        if (lane == 63) wsum[w] = v;
        __syncthreads();
        int woff = 0, ctot = 0;
        #pragma unroll
        for (int k = 0; k < 16; k++) { int s = wsum[k]; ctot += s; if (k < w) woff += s; }
        int ex = running + woff + v - m;           // exclusive prefix of "valid"
        int d = m ? ex : (NTOT - 1 - (i - ex));    // invalid packed from the back
        inv[b * NTOT + d] = i;
        maxsim[b * NTOT + i] = 0u;                 // decodes to NaN -> never confident
        running += ctot;
        __syncthreads();
    }
    if (tid == 0) { cnts[b] = running; cnts[NB + b] = NTOT - running; }
}

// ------- kernel 2: gather + normalize + write fp16 in MFMA-fragment-linear layout -------
__global__ __launch_bounds__(256) void k_norm(
    const float* __restrict__ feat, const int* __restrict__ inv, ushort* __restrict__ pk)
{
    int blk = blockIdx.x;
    int b = blk / (NTOT / 32);
    int panel = blk % (NTOT / 32);
    int tid = threadIdx.x;
    int r = tid >> 3, c = tid & 7;           // 32 rows x 8 k-slices
    int d = panel * 32 + r;
    int i = inv[b * NTOT + d];
    const float* src = feat + ((size_t)b * NTOT + i) * DIM + c * 32;

    float x[32]; float ss = 0.f;
    #pragma unroll
    for (int j = 0; j < 8; j++) {
        float4 v = *(const float4*)(src + j * 4);
        x[j*4+0] = v.x; x[j*4+1] = v.y; x[j*4+2] = v.z; x[j*4+3] = v.w;
        ss += v.x*v.x + v.y*v.y + v.z*v.z + v.w*v.w;
    }
    ss += __shfl_xor(ss, 1); ss += __shfl_xor(ss, 2); ss += __shfl_xor(ss, 4);
    float invn = 1.0f / fmaxf(sqrtf(ss), 1e-12f);

    ushort* pbout = pk + (size_t)b * NTOT * DIM;
    #pragma unroll
    for (int g = 0; g < 4; g++) {            // 4 groups of 8 halfs -> 16B stores
        f16x8 hv;
        #pragma unroll
        for (int e = 0; e < 8; e++) hv[e] = (_Float16)(x[g*8+e] * invn);
        int kc = c * 2 + (g >> 1), kh = g & 1;
        *(f16x8*)(pbout + (size_t)(panel * 16 + kc) * 512 + (kh * 32 + r) * 8) = hv;
    }
}

// -------- kernel 3: A-in-register (32 rows/wave), B-streaming fp16 MFMA GEMM --------
__global__ __launch_bounds__(1024, 4) void k_gemm(
    const ushort* __restrict__ pk, unsigned* __restrict__ maxsim, const int* __restrict__ cnts)
{
    int b = blockIdx.z;
    int nval = cnts[b];
    int ninv = cnts[NB + b];
    int bx = blockIdx.x;     // col group
    int by = blockIdx.y;     // row block (from back)
    if (bx * CGRP >= nval || by * BROWS >= ninv) return;
    int rowA0 = NTOT - (by + 1) * BROWS;
    int colG0 = bx * CGRP;
    int pA0 = rowA0 >> 5, pBg = colG0 >> 5;

    __shared__ __align__(16) char smem[4 * TILEB];   // 128 KiB B-tile ring

    int tid = threadIdx.x, lane = tid & 63, w = tid >> 6;   // 16 waves, wave w: rows rowA0+w*32
    const ushort* pb = pk + (size_t)b * NTOT * DIM;

    // ---- A fragments resident in registers: 16 k-slices = 64 VGPR ----
    f16x8 a[16];
    {
        const ushort* abase = pb + (size_t)(pA0 + w) * 16 * 512 + lane * 8;
        #pragma unroll
        for (int ks = 0; ks < 16; ks++)
            a[ks] = *(const f16x8*)(abase + (size_t)ks * 512);
    }
    __builtin_amdgcn_sched_barrier(0);

    // stage B-tile t (64 cols = 2 panels, 32 chunks of 1KB); wave w stages chunks {2w, 2w+1}
#define STAGE(t) { const int bo_ = ((t) & 3) * TILEB; const int p0_ = pBg + (t) * 2;     \
    _Pragma("unroll")                                                                    \
    for (int c_ = 0; c_ < 2; c_++) {                                                     \
        int c__ = w * 2 + c_;                                                            \
        const ushort* g__ = pb + ((size_t)(p0_ + (c__ >> 4)) * 16 + (c__ & 15)) * 512 + lane * 8; \
        load_lds16(g__, smem + bo_ + c__ * 1024);                                        \
    }                                                                                    \
    __builtin_amdgcn_sched_barrier(0); }

    STAGE(0); STAGE(1); STAGE(2);

    float mrow[16];
    #pragma unroll
    for (int rr = 0; rr < 16; rr++) mrow[rr] = -INFINITY;

    const f32x16 zacc = {};

    #pragma unroll
    for (int t = 0; t < NT; t++) {
        // wait own tile-t stage loads (2/tile/wave; keep younger tiles in flight)
        if (t <= 1)      asm volatile("s_waitcnt vmcnt(4)" ::: "memory");
        else if (t == 2) asm volatile("s_waitcnt vmcnt(2)" ::: "memory");
        else             asm volatile("s_waitcnt vmcnt(0)" ::: "memory");
        __builtin_amdgcn_s_barrier();
        __builtin_amdgcn_sched_barrier(0);
        if (t + 3 < NT) STAGE(t + 3);

        const char* sb = smem + (t & 3) * TILEB;
        #pragma unroll
        for (int nt = 0; nt < 2; nt++) {
            f32x16 acc = zacc;
            #pragma unroll
            for (int kq = 0; kq < 4; kq++) {
                f16x8 bg[4];
                #pragma unroll
                for (int k4 = 0; k4 < 4; k4++)
                    bg[k4] = *(const f16x8*)(sb + (nt * 16 + kq * 4 + k4) * 1024 + lane * 16);
                __builtin_amdgcn_s_setprio(1);
                #pragma unroll
                for (int k4 = 0; k4 < 4; k4++)
                    acc = __builtin_amdgcn_mfma_f32_32x32x16_f16(
                        a[kq * 4 + k4], bg[k4], acc, 0, 0, 0);
                __builtin_amdgcn_s_setprio(0);
            }
            // fold into running row-max (mask invalid cols)
            int cg = colG0 + t * 64 + nt * 32 + (lane & 31);
            bool cv = cg < nval;
            #pragma unroll
            for (int rr = 0; rr < 16; rr++) {
                float vv = cv ? acc[rr] : -INFINITY;
                mrow[rr] = fmaxf(mrow[rr], vv);
            }
        }
    }
#undef STAGE

    // ---- epilogue: butterfly over 32-lane col groups, one atomic per row ----
    #pragma unroll
    for (int off = 1; off <= 16; off <<= 1)
        #pragma unroll
        for (int rr = 0; rr < 16; rr++)
            mrow[rr] = fmaxf(mrow[rr], __shfl_xor(mrow[rr], off));

    int cl = lane & 31, hh = lane >> 5;
    if (cl == 0) {
        #pragma unroll
        for (int rr = 0; rr < 16; rr++) {
            int rowg = rowA0 + w * 32 + (rr & 3) + 8 * (rr >> 2) + 4 * hh;
            atomicMax(maxsim + (size_t)b * NTOT + rowg, toOrd(mrow[rr]));
        }
    }
}

// ---------------- kernel 4: finalize scalar ----------------
__global__ __launch_bounds__(1024) void k_final(
    const unsigned* __restrict__ maxsim, const int* __restrict__ cnts, float* __restrict__ out)
{
    __shared__ float ssum[NB];
    __shared__ int   scnt[NB];
    int tid = threadIdx.x;
    if (tid < NB) { ssum[tid] = 0.0f; scnt[tid] = 0; }
    __syncthreads();

    for (int b = 0; b < NB; b++) {
        int ninv = cnts[NB + b];
        float ls = 0.0f; int lc = 0;
        for (int i = tid; i < ninv; i += 1024) {
            int r = NTOT - ninv + i;
            float ms = fromOrd(maxsim[(size_t)b * NTOT + r]);
            if (ms > 0.8f) { ls += 1.0f - ms; lc++; }   // NaN-safe
        }
        #pragma unroll
        for (int off = 32; off; off >>= 1) {
            ls += __shfl_xor(ls, off);
            lc += __shfl_xor(lc, off);
        }
        if ((tid & 63) == 0) { atomicAdd(&ssum[b], ls); atomicAdd(&scnt[b], lc); }
    }
    __syncthreads();

    if (tid == 0) {
        float tl = 0.0f, tp = 0.0f;
        for (int b = 0; b < NB; b++) {
            int nval = cnts[b], ninv = cnts[NB + b], nc = scnt[b];
            bool active = (nc > 0) && (nval > 0) && (ninv > 0);
            if (active) {
                float pseudo = ssum[b] / (float)(nc > 0 ? nc : 1);
                tl += pseudo * (float)ninv;
                tp += (float)ninv;
            }
        }
        out[0] = (tp > 0.0f) ? (0.01f * tl / tp) : 0.0f;
    }
}

extern "C" void kernel_launch(void* const* d_in, const int* in_sizes, int n_in,
                              void* d_out, int out_size, void* d_ws, size_t ws_size,
                              hipStream_t stream)
{
    const float* feat = (const float*)d_in[0];
    const int*   mask = (const int*)d_in[1];

    char* ws = (char*)d_ws;
    int*      cnts   = (int*)ws;
    int*      inv    = (int*)(ws + 64);
    unsigned* maxsim = (unsigned*)(ws + 98368);
    ushort*   pk     = (ushort*)(ws + 262144);

    hipLaunchKernelGGL(k_scan, dim3(NB), dim3(1024), 0, stream, mask, inv, maxsim, cnts);
    hipLaunchKernelGGL(k_norm, dim3(NB * (NTOT / 32)), dim3(256), 0, stream, feat, inv, pk);
    hipLaunchKernelGGL(k_gemm, dim3(NGC, NRB, NB), dim3(1024), 0, stream, pk, maxsim, cnts);
    hipLaunchKernelGGL(k_final, dim3(1), dim3(1024), 0, stream, maxsim, cnts, (float*)d_out);
}